// Round 9
// baseline (345.585 us; speedup 1.0000x reference)
//
#include <hip/hip_runtime.h>

typedef unsigned short u16;
typedef unsigned int   u32;

typedef __bf16 bf16_t;
typedef bf16_t bf16x8 __attribute__((ext_vector_type(8)));
typedef float  f32x4  __attribute__((ext_vector_type(4)));

// ---------- bf16 helpers ----------
__device__ __forceinline__ float bf2f(u16 h) { return __uint_as_float(((u32)h) << 16); }
__device__ __forceinline__ u16 f2bf(float f) {
    u32 u = __float_as_uint(f);
    u32 r = u + 0x7fffu + ((u >> 16) & 1u);   // RNE
    return (u16)(r >> 16);
}
__device__ __forceinline__ void unpack2(u32 v, float& a, float& b) {
    a = __uint_as_float(v << 16);
    b = __uint_as_float(v & 0xffff0000u);
}

// Constants: B=4, T=16 (img=b*16+t), C=64, HW=64, PS=8, L=1024, D=4096
// Token map: j = t*64+(h>>3)*8+(w>>3) ; q/k feature: dd = c*64+(h&7)*8+(w&7)
// V-feature map (px-major): dd' = ((h&7)*8+(w&7))*64 + c

// ---------------------------------------------------------------------------
// K1: depthwise 3x3 q,k convs. One block per (img,c) plane; LDS-staged reads,
// 16B packed token stores.
// ---------------------------------------------------------------------------
__global__ __launch_bounds__(256) void dwconv_qk(
    const float* __restrict__ x, const float* __restrict__ qw, const float* __restrict__ qb,
    const float* __restrict__ kw, const float* __restrict__ kb,
    u16* __restrict__ qtok, u16* __restrict__ ktok)
{
    __shared__ float ts[64][65];
    int img = blockIdx.x >> 6, c = blockIdx.x & 63;
    int tid = threadIdx.x;
    const float* xp = x + ((size_t)((img << 6) + c) << 12);
    #pragma unroll
    for (int i = 0; i < 4; i++) {
        int p = i * 1024 + tid * 4;
        int r = p >> 6, col = p & 63;
        float4 v = *(const float4*)(xp + p);
        ts[r][col] = v.x; ts[r][col + 1] = v.y; ts[r][col + 2] = v.z; ts[r][col + 3] = v.w;
    }
    float qwv[9], kwv[9];
    #pragma unroll
    for (int i = 0; i < 9; i++) { qwv[i] = qw[c * 9 + i]; kwv[i] = kw[c * 9 + i]; }
    float qbb = qb[c], kbb = kb[c];
    __syncthreads();

    int r = tid >> 2, q = tid & 3;
    int b = img >> 4, t = img & 15;
    int gh = r >> 3, pr = r & 7;
    size_t base = (((size_t)(b << 10) + (t << 6) + (gh << 3)) << 12) + (c << 6) + (pr << 3);

    #pragma unroll
    for (int s = 0; s < 2; s++) {
        int gw = q * 2 + s, w0 = gw << 3;
        float qa[8], ka[8];
        #pragma unroll
        for (int i = 0; i < 8; i++) { qa[i] = qbb; ka[i] = kbb; }
        #pragma unroll
        for (int ky = 0; ky < 3; ky++) {
            int hh = r + ky - 1;
            if (hh < 0 || hh > 63) continue;
            float xr[10];
            #pragma unroll
            for (int cc = 0; cc < 10; cc++) {
                int ww = w0 - 1 + cc;
                xr[cc] = (ww < 0 || ww > 63) ? 0.f : ts[hh][ww];
            }
            #pragma unroll
            for (int kx = 0; kx < 3; kx++) {
                float wq = qwv[ky * 3 + kx], wk = kwv[ky * 3 + kx];
                #pragma unroll
                for (int i = 0; i < 8; i++) {
                    qa[i] += xr[i + kx] * wq;
                    ka[i] += xr[i + kx] * wk;
                }
            }
        }
        union { u16 h8[8]; uint4 u; } pq, pk;
        #pragma unroll
        for (int i = 0; i < 8; i++) { pq.h8[i] = f2bf(qa[i]); pk.h8[i] = f2bf(ka[i]); }
        size_t o = base + ((size_t)gw << 12);
        *(uint4*)&qtok[o] = pq.u;
        *(uint4*)&ktok[o] = pk.u;
    }
}

// ---------------------------------------------------------------------------
// Prep A: x f32 NCHW -> xb bf16 NHWC
// ---------------------------------------------------------------------------
__global__ __launch_bounds__(256) void nchw_to_nhwc(
    const float* __restrict__ x, u16* __restrict__ xb)
{
    __shared__ float ts[64][65];
    int img = blockIdx.x >> 6, h = blockIdx.x & 63;
    int tid = threadIdx.x;
    const float* xp = x + ((size_t)img << 18) + (h << 6);
    int c = tid >> 2, wg = (tid & 3) << 4;
    #pragma unroll
    for (int i = 0; i < 4; i++) {
        float4 v = *(const float4*)(xp + ((size_t)c << 12) + wg + i * 4);
        ts[c][wg + i * 4 + 0] = v.x; ts[c][wg + i * 4 + 1] = v.y;
        ts[c][wg + i * 4 + 2] = v.z; ts[c][wg + i * 4 + 3] = v.w;
    }
    __syncthreads();
    int w = tid >> 2, cg = (tid & 3) << 4;
    union { u16 h8[8]; uint4 u; } p0, p1;
    #pragma unroll
    for (int m = 0; m < 8; m++) {
        p0.h8[m] = f2bf(ts[cg + m][w]);
        p1.h8[m] = f2bf(ts[cg + 8 + m][w]);
    }
    u16* dst = xb + (((((size_t)img << 6) + h) << 6) + w) * 64 + cg;
    *(uint4*)dst       = p0.u;
    *(uint4*)(dst + 8) = p1.u;
}

// ---------------------------------------------------------------------------
// Prep B: both weight tensors f32 [cout][cin][3][3] -> bf16
// Layout: wt[tap][kbg(8)][cout(64)][s(8)]  (cin = kbg*8+s), 4096 u16/tap.
// ---------------------------------------------------------------------------
__global__ __launch_bounds__(256) void weight_prep2(
    const float* __restrict__ vw, const float* __restrict__ cw, u16* __restrict__ wt)
{
    int e = blockIdx.x * 256 + threadIdx.x;
    if (e >= 73728) return;
    int half = e >= 36864;
    int e2 = e - (half ? 36864 : 0);
    int tap = e2 >> 12;
    int kbg = (e2 >> 9) & 7;
    int cout = (e2 >> 3) & 63;
    int s = e2 & 7;
    int cin = (kbg << 3) + s;
    const float* src = half ? cw : vw;
    wt[e] = f2bf(src[((cout << 6) + cin) * 9 + tap]);
}

// ---------------------------------------------------------------------------
// MFMA 3x3 conv v3 (round-6 known-good). Block = 1 img x 8 h-rows, 4 waves
// (2 rows/wave, 8 B-frags). All inner-loop loads from LDS.
// ---------------------------------------------------------------------------
template<bool IS_C>
__global__ __launch_bounds__(256, 2) void conv_mfma(
    const u16* __restrict__ xb, const u16* __restrict__ wt,
    const float* __restrict__ bias, const float* __restrict__ xres,
    u16* __restrict__ vt, float* __restrict__ out)
{
    __shared__ u16 xs[21120];   // 10 x 2112 u16 (4224B rows); reused by epilogue
    __shared__ u16 wl[18432];   // [tap9][kb4][cout64][8]

    int tid = threadIdx.x, lane = tid & 63, wv = tid >> 6;
    int img = blockIdx.x >> 3, rowblk = blockIdx.x & 7;
    int h0 = rowblk << 3;
    int r16 = lane & 15, kb = lane >> 4;

    const uint4 z4 = make_uint4(0, 0, 0, 0);
    for (int i = tid; i < 80; i += 256) {
        int r = i >> 3, k = i & 7;
        *(uint4*)&xs[r * 2112 + 2048 + k * 8] = z4;
    }
    if (rowblk == 0)
        for (int i = tid; i < 264; i += 256) *(uint4*)&xs[i * 8] = z4;
    if (rowblk == 7)
        for (int i = tid; i < 264; i += 256) *(uint4*)&xs[9 * 2112 + i * 8] = z4;

    int pxoff[4][3];
    #pragma unroll
    for (int g = 0; g < 4; g++) {
        #pragma unroll
        for (int dx = 0; dx < 3; dx++) {
            int cc = g * 16 + r16 + dx - 1;
            int off;
            if (cc < 0)        off = 2048 + kb * 8;
            else if (cc >= 64) off = 2080 + kb * 8;
            else               off = (cc >> 4) * 512 + kb * 128 + (cc & 15) * 8;
            pxoff[g][dx] = off;
        }
    }

    const u16* xb_i = xb + ((size_t)img << 18);

    f32x4 acc[4][8] = {};

    for (int c0 = 0; c0 < 64; c0 += 32) {
        __syncthreads();
        #pragma unroll
        for (int k = 0; k < 10; k++) {
            int i = wv + (k << 2);
            int r = i >> 2, g = i & 3;
            int h = h0 + r - 1;
            if (h >= 0 && h < 64) {
                const u16* src = xb_i + (size_t)(((h << 6) + (g << 4) + r16) << 6)
                                 + c0 + (kb << 3);
                u16* dst = xs + r * 2112 + g * 512;
                __builtin_amdgcn_global_load_lds(
                    (const __attribute__((address_space(1))) u32*)src,
                    (__attribute__((address_space(3))) u32*)dst, 16, 0, 0);
            }
        }
        #pragma unroll
        for (int tp = 0; tp < 9; tp++) {
            const u16* srcw = wt + tp * 4096 + (c0 << 6) + tid * 8;
            u16* dstw = wl + tp * 2048 + (wv << 9);
            __builtin_amdgcn_global_load_lds(
                (const __attribute__((address_space(1))) u32*)srcw,
                (__attribute__((address_space(3))) u32*)dstw, 16, 0, 0);
        }
        __syncthreads();

        #pragma unroll
        for (int dy = 0; dy < 3; dy++) {
            #pragma unroll
            for (int dx = 0; dx < 3; dx++) {
                int tap = dy * 3 + dx;
                bf16x8 af[4];
                #pragma unroll
                for (int m = 0; m < 4; m++)
                    af[m] = *(const bf16x8*)&wl[tap * 2048 + (kb << 9)
                                                + (((m << 4) + r16) << 3)];
                #pragma unroll
                for (int nf = 0; nf < 8; nf++) {
                    int rowb = ((wv << 1) + (nf >> 2) + dy) * 2112;
                    bf16x8 bv = *(const bf16x8*)&xs[rowb + pxoff[nf & 3][dx]];
                    #pragma unroll
                    for (int m = 0; m < 4; m++)
                        acc[m][nf] = __builtin_amdgcn_mfma_f32_16x16x32_bf16(
                            af[m], bv, acc[m][nf], 0, 0, 0);
                }
            }
        }
    }

    int b = img >> 4, t = img & 15;
    if constexpr (!IS_C) {
        __syncthreads();
        u16* wbuf = xs + (wv << 12);
        int j0 = (t << 6) + (rowblk << 3);
        #pragma unroll
        for (int mh = 0; mh < 2; mh++) {
            #pragma unroll
            for (int mm = 0; mm < 2; mm++) {
                int m = mh * 2 + mm;
                #pragma unroll
                for (int q = 0; q < 4; q++) {
                    int cm = mm * 16 + (kb << 2) + q;
                    float bvs = bias[mh * 32 + cm];
                    #pragma unroll
                    for (int nf = 0; nf < 8; nf++) {
                        int lrL = nf >> 2;
                        int pc  = r16 & 7;
                        int gw  = ((nf & 3) << 1) | (r16 >> 3);
                        wbuf[(((cm << 1) | lrL) << 6) + (pc << 3) + gw] =
                            f2bf(acc[m][nf][q] + bvs);
                    }
                }
            }
            #pragma unroll
            for (int it = 0; it < 8; it++) {
                int cid = it * 64 + lane;
                int cm  = cid >> 4;
                int lrL = (cid >> 3) & 1;
                int pc  = cid & 7;
                int lr  = (wv << 1) | lrL;
                int cout = mh * 32 + cm;
                int dd  = (((lr << 3) | pc) << 6) | cout;
                uint4 val = *(uint4*)&wbuf[cid << 3];
                *(uint4*)&vt[(((size_t)((b << 12) + dd)) << 10) + j0] = val;
            }
            if (mh == 0) __syncthreads();
        }
    } else {
        #pragma unroll
        for (int m = 0; m < 4; m++) {
            #pragma unroll
            for (int q = 0; q < 4; q++) {
                int cout = (m << 4) + (kb << 2) + q;
                float bvs = bias[cout];
                #pragma unroll
                for (int nf = 0; nf < 8; nf++) {
                    int lr = (wv << 1) + (nf >> 2);
                    int w = (nf & 3) * 16 + r16;
                    int h = h0 + lr;
                    size_t o = ((size_t)((img << 6) + cout) << 12) + (h << 6) + w;
                    out[o] = acc[m][nf][q] + bvs + xres[o];
                }
            }
        }
    }
}

// ---------------------------------------------------------------------------
// MFMA GEMM: C = A·B^T, TM x TN tile, BK=64, 4 waves (2x2), 16x16x32 MFMA.
// v3 pipeline (T3/T4): 3 LDS buffers, depth-2 prefetch, COUNTED vmcnt(6)
// (= the 6 loads/wave just issued for tile s+2; forces tile s+1 to land) +
// raw s_barrier. Never drains to vmcnt(0) in the main loop.
// XCD-chunked bijective block swizzle (grid % 8 == 0).
// EPI 0: C = bf16(exp(acc/64))               (probs)
// EPI 2: C = bf16(acc * invl[row]) -> NHWC axb  (j = dd' = ppos*64+c)
// ---------------------------------------------------------------------------
template<int TM, int TN, int LDA, int LDB, int LDC, int KTOT, int MT, int NT,
         int EPI, int OCC>
__global__ __launch_bounds__(256, OCC) void mfma_abt(
    const u16* __restrict__ Ag, const u16* __restrict__ Bg,
    const float* __restrict__ invl, u16* __restrict__ Cg)
{
    constexpr int MF = TM / 32;
    constexpr int NF = TN / 32;
    constexpr int KSTEPS = KTOT / 64;
    constexpr int NWG = 4 * MT * NT;
    constexpr int CPX = NWG / 8;
    static_assert(MF + NF == 6, "counted vmcnt(6) assumes 6 loads/wave/stage");
    static_assert(KSTEPS >= 3, "pipeline needs >=3 K-steps");
    __shared__ u16 As[3][TM * 64];
    __shared__ u16 Bs[3][TN * 64];

    int tid  = threadIdx.x;
    int lane = tid & 63, wv = tid >> 6;
    int bid  = blockIdx.x;
    int id   = (bid & 7) * CPX + (bid >> 3);   // XCD-chunked bijective remap
    int nt   = id % NT;
    int rest = id / NT;
    int mt   = rest % MT;
    int bi   = rest / MT;

    const u16* Ab = Ag + (size_t)bi * (1024 * (size_t)LDA) + (size_t)(mt * TM) * LDA;
    const u16* Bb = Bg + (size_t)bi * ((size_t)NT * TN * LDB) + (size_t)(nt * TN) * LDB;

    int srow = tid >> 3;
    int slot = tid & 7;
    int wr = wv >> 1, wc = wv & 1;
    int r16 = lane & 15, kb = lane >> 4;

    f32x4 acc[MF][NF] = {};

    // staging: tile k0 into buffer bsel (6 global_load_lds per wave)
    auto STAGE = [&](int bsel, int k0) {
        #pragma unroll
        for (int it = 0; it < MF; it++) {
            int rl = it * 32 + srow;
            int kg = slot ^ (rl & 7);
            const u16* sa = Ab + (size_t)rl * LDA + k0 + kg * 8;
            u16* da = &As[bsel][it * 2048 + wv * 512];
            __builtin_amdgcn_global_load_lds(
                (const __attribute__((address_space(1))) u32*)sa,
                (__attribute__((address_space(3))) u32*)da, 16, 0, 0);
        }
        #pragma unroll
        for (int it = 0; it < NF; it++) {
            int rl = it * 32 + srow;
            int kg = slot ^ (rl & 7);
            const u16* sb = Bb + (size_t)rl * LDB + k0 + kg * 8;
            u16* db = &Bs[bsel][it * 2048 + wv * 512];
            __builtin_amdgcn_global_load_lds(
                (const __attribute__((address_space(1))) u32*)sb,
                (__attribute__((address_space(3))) u32*)db, 16, 0, 0);
        }
    };

    // prologue: tiles 0 and 1 in flight; wait for tile 0 only
    STAGE(0, 0);
    STAGE(1, 64);
    asm volatile("s_waitcnt vmcnt(6)" ::: "memory");
    __builtin_amdgcn_s_barrier();
    asm volatile("" ::: "memory");

    for (int s = 0; s < KSTEPS; s++) {
        int cur = s % 3;
        if (s + 2 < KSTEPS) STAGE((s + 2) % 3, (s + 2) * 64);

        const char* Ac = (const char*)&As[cur][0];
        const char* Bc = (const char*)&Bs[cur][0];
        #pragma unroll
        for (int kk = 0; kk < 2; kk++) {
            bf16x8 af[MF], bfr[NF];
            #pragma unroll
            for (int m = 0; m < MF; m++) {
                int row  = wr * (TM / 2) + m * 16 + r16;
                int boff = row * 128 + (((kk * 32 + kb * 8) * 2) ^ ((row & 7) << 4));
                af[m] = *(const bf16x8*)(Ac + boff);
            }
            #pragma unroll
            for (int n = 0; n < NF; n++) {
                int row  = wc * (TN / 2) + n * 16 + r16;
                int boff = row * 128 + (((kk * 32 + kb * 8) * 2) ^ ((row & 7) << 4));
                bfr[n] = *(const bf16x8*)(Bc + boff);
            }
            #pragma unroll
            for (int m = 0; m < MF; m++)
                #pragma unroll
                for (int n = 0; n < NF; n++)
                    acc[m][n] = __builtin_amdgcn_mfma_f32_16x16x32_bf16(
                        af[m], bfr[n], acc[m][n], 0, 0, 0);
        }

        // tile s+1 must be resident before next iteration's reads:
        // steady state keeps the 6 loads for tile s+2 in flight (never drain).
        if (s + 2 < KSTEPS)
            asm volatile("s_waitcnt vmcnt(6)" ::: "memory");
        else
            asm volatile("s_waitcnt vmcnt(0)" ::: "memory");
        __builtin_amdgcn_s_barrier();
        asm volatile("" ::: "memory");
    }

    size_t crow0 = (size_t)bi * 1024 + (size_t)mt * TM + wr * (TM / 2);
    int col0 = nt * TN + wc * (TN / 2);
    #pragma unroll
    for (int m = 0; m < MF; m++) {
        float il[4] = {1.f, 1.f, 1.f, 1.f};
        if constexpr (EPI == 2) {
            #pragma unroll
            for (int q = 0; q < 4; q++)
                il[q] = invl[crow0 + m * 16 + kb * 4 + q];
        }
        #pragma unroll
        for (int n = 0; n < NF; n++) {
            #pragma unroll
            for (int q = 0; q < 4; q++) {
                int i_loc = m * 16 + kb * 4 + q;
                int j     = col0 + n * 16 + r16;
                float v   = acc[m][n][q];
                if constexpr (EPI == 0) {
                    Cg[(crow0 + i_loc) * (size_t)LDC + j] = f2bf(__expf(v * 0.015625f));
                } else {
                    int i2 = mt * TM + wr * (TM / 2) + i_loc;
                    int t = i2 >> 6, patch = i2 & 63;
                    int c = j & 63, pr = (j >> 9) & 7, pc = (j >> 6) & 7;
                    int hh = ((patch >> 3) << 3) + pr, w2 = ((patch & 7) << 3) + pc;
                    size_t o = ((((size_t)(bi * 16 + t) << 6) + hh) << 6) + w2;
                    Cg[(o << 6) + c] = f2bf(v * il[q]);
                }
            }
        }
    }
}

// ---------------------------------------------------------------------------
// K4: invl[row] = 1 / sum_j probs~[row][j]
// ---------------------------------------------------------------------------
__global__ __launch_bounds__(256) void rowsum_inv_kernel(
    const u16* __restrict__ p, float* __restrict__ invl)
{
    int row = blockIdx.x, tid = threadIdx.x;
    uint2 v = ((const uint2*)(p + ((size_t)row << 10)))[tid];
    float a, b, c, d;
    unpack2(v.x, a, b); unpack2(v.y, c, d);
    float s = (a + b) + (c + d);
    #pragma unroll
    for (int off = 32; off; off >>= 1) s += __shfl_xor(s, off);
    __shared__ float rs[4];
    if ((tid & 63) == 0) rs[tid >> 6] = s;
    __syncthreads();
    if (tid == 0) invl[row] = 1.f / ((rs[0] + rs[1]) + (rs[2] + rs[3]));
}

// ---------------------------------------------------------------------------
// Buffers:
//   A = d_out[0,32MB): qtok -> vt' (conv_v out) -> overwritten by f32 out
//   B = ws[0,32MB)   : ktok -> xb (NHWC bf16)  -> axb (NHWC bf16)
//   C = ws[32,40MB)  : probs
//   invl = ws[40MB,+16KB); wt = ws[40MB+64KB,+144KB)
// Order: wprep, dwconv -> scores -> rowsum -> nhwc -> conv_v -> ax -> conv_c
// ---------------------------------------------------------------------------
extern "C" void kernel_launch(void* const* d_in, const int* in_sizes, int n_in,
                              void* d_out, int out_size, void* d_ws, size_t ws_size,
                              hipStream_t stream)
{
    const float* x  = (const float*)d_in[0];
    const float* qw = (const float*)d_in[1];
    const float* qb = (const float*)d_in[2];
    const float* kw = (const float*)d_in[3];
    const float* kb = (const float*)d_in[4];
    const float* vw = (const float*)d_in[5];
    const float* vb = (const float*)d_in[6];
    const float* cw = (const float*)d_in[7];
    const float* cb = (const float*)d_in[8];
    float* out = (float*)d_out;

    char* ws = (char*)d_ws;
    u16*   qtok  = (u16*)d_out;                              // region A
    u16*   ktok  = (u16*)ws;                                 // region B
    u16*   probs = (u16*)(ws + (size_t)32 * 1024 * 1024);    // region C
    float* invl  = (float*)(ws + (size_t)40 * 1024 * 1024);
    u16*   wtv   = (u16*)(ws + (size_t)40 * 1024 * 1024 + 65536);
    u16*   wtc   = wtv + 36864;
    u16*   xbuf  = ktok;                                     // B (after scores)
    u16*   vt    = qtok;                                     // A (after scores)
    u16*   axb   = ktok;                                     // B (after conv_v)

    weight_prep2<<<288, 256, 0, stream>>>(vw, cw, wtv);

    dwconv_qk<<<4096, 256, 0, stream>>>(x, qw, qb, kw, kb, qtok, ktok);

    // scores: 64x128 tiles, 3-buf pipeline (72KB), grid 512
    mfma_abt<64, 128, 4096, 4096, 1024, 4096, 16, 8, 0, 2><<<512, 256, 0, stream>>>(
        qtok, ktok, nullptr, probs);

    rowsum_inv_kernel<<<4096, 256, 0, stream>>>(probs, invl);

    nchw_to_nhwc<<<4096, 256, 0, stream>>>(x, xbuf);

    conv_mfma<false><<<512, 256, 0, stream>>>(xbuf, wtv, vb, nullptr, vt, nullptr);

    // ax: 128x64 tiles, 3-buf pipeline (72KB), grid 2048
    mfma_abt<128, 64, 1024, 1024, 4096, 1024, 8, 64, 2, 2><<<2048, 256, 0, stream>>>(
        probs, vt, invl, axb);

    conv_mfma<true><<<512, 256, 0, stream>>>(axb, wtc, cb, x, nullptr, out);
}

// Round 10
// 302.418 us; speedup vs baseline: 1.1427x; 1.1427x over previous
//
#include <hip/hip_runtime.h>

typedef unsigned short u16;
typedef unsigned int   u32;

typedef __bf16 bf16_t;
typedef bf16_t bf16x8 __attribute__((ext_vector_type(8)));
typedef float  f32x4  __attribute__((ext_vector_type(4)));

// ---------- bf16 helpers ----------
__device__ __forceinline__ float bf2f(u16 h) { return __uint_as_float(((u32)h) << 16); }
__device__ __forceinline__ u16 f2bf(float f) {
    u32 u = __float_as_uint(f);
    u32 r = u + 0x7fffu + ((u >> 16) & 1u);   // RNE
    return (u16)(r >> 16);
}
__device__ __forceinline__ void unpack2(u32 v, float& a, float& b) {
    a = __uint_as_float(v << 16);
    b = __uint_as_float(v & 0xffff0000u);
}

// Constants: B=4, T=16 (img=b*16+t), C=64, HW=64, PS=8, L=1024, D=4096
// Token map: j = t*64+(h>>3)*8+(w>>3) ; q/k feature: dd = c*64+(h&7)*8+(w&7)
// V-feature map (px-major): dd' = ((h&7)*8+(w&7))*64 + c

// ---------------------------------------------------------------------------
// K1: depthwise 3x3 q,k convs. One block per (img,c) plane; LDS-staged reads,
// 16B packed token stores. (block writes full vt-lines: no write amp)
// ---------------------------------------------------------------------------
__global__ __launch_bounds__(256) void dwconv_qk(
    const float* __restrict__ x, const float* __restrict__ qw, const float* __restrict__ qb,
    const float* __restrict__ kw, const float* __restrict__ kb,
    u16* __restrict__ qtok, u16* __restrict__ ktok)
{
    __shared__ float ts[64][65];
    int img = blockIdx.x >> 6, c = blockIdx.x & 63;
    int tid = threadIdx.x;
    const float* xp = x + ((size_t)((img << 6) + c) << 12);
    #pragma unroll
    for (int i = 0; i < 4; i++) {
        int p = i * 1024 + tid * 4;
        int r = p >> 6, col = p & 63;
        float4 v = *(const float4*)(xp + p);
        ts[r][col] = v.x; ts[r][col + 1] = v.y; ts[r][col + 2] = v.z; ts[r][col + 3] = v.w;
    }
    float qwv[9], kwv[9];
    #pragma unroll
    for (int i = 0; i < 9; i++) { qwv[i] = qw[c * 9 + i]; kwv[i] = kw[c * 9 + i]; }
    float qbb = qb[c], kbb = kb[c];
    __syncthreads();

    int r = tid >> 2, q = tid & 3;
    int b = img >> 4, t = img & 15;
    int gh = r >> 3, pr = r & 7;
    size_t base = (((size_t)(b << 10) + (t << 6) + (gh << 3)) << 12) + (c << 6) + (pr << 3);

    #pragma unroll
    for (int s = 0; s < 2; s++) {
        int gw = q * 2 + s, w0 = gw << 3;
        float qa[8], ka[8];
        #pragma unroll
        for (int i = 0; i < 8; i++) { qa[i] = qbb; ka[i] = kbb; }
        #pragma unroll
        for (int ky = 0; ky < 3; ky++) {
            int hh = r + ky - 1;
            if (hh < 0 || hh > 63) continue;
            float xr[10];
            #pragma unroll
            for (int cc = 0; cc < 10; cc++) {
                int ww = w0 - 1 + cc;
                xr[cc] = (ww < 0 || ww > 63) ? 0.f : ts[hh][ww];
            }
            #pragma unroll
            for (int kx = 0; kx < 3; kx++) {
                float wq = qwv[ky * 3 + kx], wk = kwv[ky * 3 + kx];
                #pragma unroll
                for (int i = 0; i < 8; i++) {
                    qa[i] += xr[i + kx] * wq;
                    ka[i] += xr[i + kx] * wk;
                }
            }
        }
        union { u16 h8[8]; uint4 u; } pq, pk;
        #pragma unroll
        for (int i = 0; i < 8; i++) { pq.h8[i] = f2bf(qa[i]); pk.h8[i] = f2bf(ka[i]); }
        size_t o = base + ((size_t)gw << 12);
        *(uint4*)&qtok[o] = pq.u;
        *(uint4*)&ktok[o] = pk.u;
    }
}

// ---------------------------------------------------------------------------
// Prep A: x f32 NCHW -> xb bf16 NHWC
// ---------------------------------------------------------------------------
__global__ __launch_bounds__(256) void nchw_to_nhwc(
    const float* __restrict__ x, u16* __restrict__ xb)
{
    __shared__ float ts[64][65];
    int img = blockIdx.x >> 6, h = blockIdx.x & 63;
    int tid = threadIdx.x;
    const float* xp = x + ((size_t)img << 18) + (h << 6);
    int c = tid >> 2, wg = (tid & 3) << 4;
    #pragma unroll
    for (int i = 0; i < 4; i++) {
        float4 v = *(const float4*)(xp + ((size_t)c << 12) + wg + i * 4);
        ts[c][wg + i * 4 + 0] = v.x; ts[c][wg + i * 4 + 1] = v.y;
        ts[c][wg + i * 4 + 2] = v.z; ts[c][wg + i * 4 + 3] = v.w;
    }
    __syncthreads();
    int w = tid >> 2, cg = (tid & 3) << 4;
    union { u16 h8[8]; uint4 u; } p0, p1;
    #pragma unroll
    for (int m = 0; m < 8; m++) {
        p0.h8[m] = f2bf(ts[cg + m][w]);
        p1.h8[m] = f2bf(ts[cg + 8 + m][w]);
    }
    u16* dst = xb + (((((size_t)img << 6) + h) << 6) + w) * 64 + cg;
    *(uint4*)dst       = p0.u;
    *(uint4*)(dst + 8) = p1.u;
}

// ---------------------------------------------------------------------------
// Prep B: both weight tensors f32 [cout][cin][3][3] -> bf16
// Layout: wt[tap][kbg(8)][cout(64)][s(8)]  (cin = kbg*8+s), 4096 u16/tap.
// ---------------------------------------------------------------------------
__global__ __launch_bounds__(256) void weight_prep2(
    const float* __restrict__ vw, const float* __restrict__ cw, u16* __restrict__ wt)
{
    int e = blockIdx.x * 256 + threadIdx.x;
    if (e >= 73728) return;
    int half = e >= 36864;
    int e2 = e - (half ? 36864 : 0);
    int tap = e2 >> 12;
    int kbg = (e2 >> 9) & 7;
    int cout = (e2 >> 3) & 63;
    int s = e2 & 7;
    int cin = (kbg << 3) + s;
    const float* src = half ? cw : vw;
    wt[e] = f2bf(src[((cout << 6) + cin) * 9 + tap]);
}

// ---------------------------------------------------------------------------
// MFMA 3x3 conv v3 (round-6 known-good) + XCD-grouped block remap:
// virt = (bid&7)*64 + bid>>3  ->  all 8 rowblks of one img share an XCD, so
// the 8 co-writers of each vt'[dd] 128B line merge in that XCD's L2
// (kills the measured 3.7x write amplification).
// Block = 1 img x 8 h-rows, 4 waves (2 rows/wave, 8 B-frags); all inner-loop
// loads from LDS (input block-transposed; weights staged).
// ---------------------------------------------------------------------------
template<bool IS_C>
__global__ __launch_bounds__(256, 2) void conv_mfma(
    const u16* __restrict__ xb, const u16* __restrict__ wt,
    const float* __restrict__ bias, const float* __restrict__ xres,
    u16* __restrict__ vt, float* __restrict__ out)
{
    __shared__ u16 xs[21120];   // 10 x 2112 u16 (4224B rows); reused by epilogue
    __shared__ u16 wl[18432];   // [tap9][kb4][cout64][8]

    int tid = threadIdx.x, lane = tid & 63, wv = tid >> 6;
    int bid = blockIdx.x;
    int virt = (bid & 7) * 64 + (bid >> 3);      // XCD grouping (grid=512)
    int img = virt >> 3, rowblk = virt & 7;
    int h0 = rowblk << 3;
    int r16 = lane & 15, kb = lane >> 4;

    const uint4 z4 = make_uint4(0, 0, 0, 0);
    for (int i = tid; i < 80; i += 256) {
        int r = i >> 3, k = i & 7;
        *(uint4*)&xs[r * 2112 + 2048 + k * 8] = z4;
    }
    if (rowblk == 0)
        for (int i = tid; i < 264; i += 256) *(uint4*)&xs[i * 8] = z4;
    if (rowblk == 7)
        for (int i = tid; i < 264; i += 256) *(uint4*)&xs[9 * 2112 + i * 8] = z4;

    int pxoff[4][3];
    #pragma unroll
    for (int g = 0; g < 4; g++) {
        #pragma unroll
        for (int dx = 0; dx < 3; dx++) {
            int cc = g * 16 + r16 + dx - 1;
            int off;
            if (cc < 0)        off = 2048 + kb * 8;
            else if (cc >= 64) off = 2080 + kb * 8;
            else               off = (cc >> 4) * 512 + kb * 128 + (cc & 15) * 8;
            pxoff[g][dx] = off;
        }
    }

    const u16* xb_i = xb + ((size_t)img << 18);

    f32x4 acc[4][8] = {};

    for (int c0 = 0; c0 < 64; c0 += 32) {
        __syncthreads();
        #pragma unroll
        for (int k = 0; k < 10; k++) {
            int i = wv + (k << 2);
            int r = i >> 2, g = i & 3;
            int h = h0 + r - 1;
            if (h >= 0 && h < 64) {
                const u16* src = xb_i + (size_t)(((h << 6) + (g << 4) + r16) << 6)
                                 + c0 + (kb << 3);
                u16* dst = xs + r * 2112 + g * 512;
                __builtin_amdgcn_global_load_lds(
                    (const __attribute__((address_space(1))) u32*)src,
                    (__attribute__((address_space(3))) u32*)dst, 16, 0, 0);
            }
        }
        #pragma unroll
        for (int tp = 0; tp < 9; tp++) {
            const u16* srcw = wt + tp * 4096 + (c0 << 6) + tid * 8;
            u16* dstw = wl + tp * 2048 + (wv << 9);
            __builtin_amdgcn_global_load_lds(
                (const __attribute__((address_space(1))) u32*)srcw,
                (__attribute__((address_space(3))) u32*)dstw, 16, 0, 0);
        }
        __syncthreads();

        #pragma unroll
        for (int dy = 0; dy < 3; dy++) {
            #pragma unroll
            for (int dx = 0; dx < 3; dx++) {
                int tap = dy * 3 + dx;
                bf16x8 af[4];
                #pragma unroll
                for (int m = 0; m < 4; m++)
                    af[m] = *(const bf16x8*)&wl[tap * 2048 + (kb << 9)
                                                + (((m << 4) + r16) << 3)];
                #pragma unroll
                for (int nf = 0; nf < 8; nf++) {
                    int rowb = ((wv << 1) + (nf >> 2) + dy) * 2112;
                    bf16x8 bv = *(const bf16x8*)&xs[rowb + pxoff[nf & 3][dx]];
                    #pragma unroll
                    for (int m = 0; m < 4; m++)
                        acc[m][nf] = __builtin_amdgcn_mfma_f32_16x16x32_bf16(
                            af[m], bv, acc[m][nf], 0, 0, 0);
                }
            }
        }
    }

    int b = img >> 4, t = img & 15;
    if constexpr (!IS_C) {
        __syncthreads();
        u16* wbuf = xs + (wv << 12);
        int j0 = (t << 6) + (rowblk << 3);
        #pragma unroll
        for (int mh = 0; mh < 2; mh++) {
            #pragma unroll
            for (int mm = 0; mm < 2; mm++) {
                int m = mh * 2 + mm;
                #pragma unroll
                for (int q = 0; q < 4; q++) {
                    int cm = mm * 16 + (kb << 2) + q;
                    float bvs = bias[mh * 32 + cm];
                    #pragma unroll
                    for (int nf = 0; nf < 8; nf++) {
                        int lrL = nf >> 2;
                        int pc  = r16 & 7;
                        int gw  = ((nf & 3) << 1) | (r16 >> 3);
                        wbuf[(((cm << 1) | lrL) << 6) + (pc << 3) + gw] =
                            f2bf(acc[m][nf][q] + bvs);
                    }
                }
            }
            #pragma unroll
            for (int it = 0; it < 8; it++) {
                int cid = it * 64 + lane;
                int cm  = cid >> 4;
                int lrL = (cid >> 3) & 1;
                int pc  = cid & 7;
                int lr  = (wv << 1) | lrL;
                int cout = mh * 32 + cm;
                int dd  = (((lr << 3) | pc) << 6) | cout;
                uint4 val = *(uint4*)&wbuf[cid << 3];
                *(uint4*)&vt[(((size_t)((b << 12) + dd)) << 10) + j0] = val;
            }
            if (mh == 0) __syncthreads();
        }
    } else {
        #pragma unroll
        for (int m = 0; m < 4; m++) {
            #pragma unroll
            for (int q = 0; q < 4; q++) {
                int cout = (m << 4) + (kb << 2) + q;
                float bvs = bias[cout];
                #pragma unroll
                for (int nf = 0; nf < 8; nf++) {
                    int lr = (wv << 1) + (nf >> 2);
                    int w = (nf & 3) * 16 + r16;
                    int h = h0 + lr;
                    size_t o = ((size_t)((img << 6) + cout) << 12) + (h << 6) + w;
                    out[o] = acc[m][nf][q] + bvs + xres[o];
                }
            }
        }
    }
}

// ---------------------------------------------------------------------------
// MFMA GEMM (round-6 2-barrier structure + XCD swizzle): C = A·B^T,
// TM x TN tile, BK=64, 4 waves (2x2), 16x16x32 MFMA, global_load_lds +
// src-side swizzle.
// EPI 0: C = bf16(exp(acc/64)); fused row-sum (shfl reduce + atomicAdd rs).
// EPI 2: C = bf16(acc / rs[row]) -> NHWC axb  (j = dd' = ppos*64+c)
// ---------------------------------------------------------------------------
template<int TM, int TN, int LDA, int LDB, int LDC, int KTOT, int MT, int NT,
         int EPI, int OCC>
__global__ __launch_bounds__(256, OCC) void mfma_abt(
    const u16* __restrict__ Ag, const u16* __restrict__ Bg,
    float* __restrict__ rs, u16* __restrict__ Cg)
{
    constexpr int MF = TM / 32;
    constexpr int NF = TN / 32;
    constexpr int NWG = 4 * MT * NT;
    constexpr int CPX = NWG / 8;
    __shared__ u16 As[TM * 64];
    __shared__ u16 Bs[TN * 64];

    int tid  = threadIdx.x;
    int lane = tid & 63, wv = tid >> 6;
    int bid  = blockIdx.x;
    int id   = (bid & 7) * CPX + (bid >> 3);   // XCD-chunked bijective remap
    int nt   = id % NT;
    int rest = id / NT;
    int mt   = rest % MT;
    int bi   = rest / MT;

    const u16* Ab = Ag + (size_t)bi * (1024 * (size_t)LDA) + (size_t)(mt * TM) * LDA;
    const u16* Bb = Bg + (size_t)bi * ((size_t)NT * TN * LDB) + (size_t)(nt * TN) * LDB;

    int srow = tid >> 3;
    int slot = tid & 7;
    int wr = wv >> 1, wc = wv & 1;
    int r16 = lane & 15, kb = lane >> 4;

    f32x4 acc[MF][NF] = {};

    for (int k0 = 0; k0 < KTOT; k0 += 64) {
        __syncthreads();
        #pragma unroll
        for (int it = 0; it < MF; it++) {
            int rl = it * 32 + srow;
            int kg = slot ^ (rl & 7);
            const u16* sa = Ab + (size_t)rl * LDA + k0 + kg * 8;
            u16* da = As + it * 2048 + wv * 512;
            __builtin_amdgcn_global_load_lds(
                (const __attribute__((address_space(1))) u32*)sa,
                (__attribute__((address_space(3))) u32*)da, 16, 0, 0);
        }
        #pragma unroll
        for (int it = 0; it < NF; it++) {
            int rl = it * 32 + srow;
            int kg = slot ^ (rl & 7);
            const u16* sb = Bb + (size_t)rl * LDB + k0 + kg * 8;
            u16* db = Bs + it * 2048 + wv * 512;
            __builtin_amdgcn_global_load_lds(
                (const __attribute__((address_space(1))) u32*)sb,
                (__attribute__((address_space(3))) u32*)db, 16, 0, 0);
        }
        __syncthreads();

        #pragma unroll
        for (int kk = 0; kk < 2; kk++) {
            bf16x8 af[MF], bfr[NF];
            #pragma unroll
            for (int m = 0; m < MF; m++) {
                int row  = wr * (TM / 2) + m * 16 + r16;
                int boff = row * 128 + (((kk * 32 + kb * 8) * 2) ^ ((row & 7) << 4));
                af[m] = *(const bf16x8*)((const char*)As + boff);
            }
            #pragma unroll
            for (int n = 0; n < NF; n++) {
                int row  = wc * (TN / 2) + n * 16 + r16;
                int boff = row * 128 + (((kk * 32 + kb * 8) * 2) ^ ((row & 7) << 4));
                bfr[n] = *(const bf16x8*)((const char*)Bs + boff);
            }
            #pragma unroll
            for (int m = 0; m < MF; m++)
                #pragma unroll
                for (int n = 0; n < NF; n++)
                    acc[m][n] = __builtin_amdgcn_mfma_f32_16x16x32_bf16(
                        af[m], bfr[n], acc[m][n], 0, 0, 0);
        }
    }

    size_t crow0 = (size_t)bi * 1024 + (size_t)mt * TM + wr * (TM / 2);
    int col0 = nt * TN + wc * (TN / 2);
    if constexpr (EPI == 0) {
        // probs + fused row-sum (sums the ROUNDED bf16 values = old semantics)
        #pragma unroll
        for (int m = 0; m < MF; m++) {
            #pragma unroll
            for (int q = 0; q < 4; q++) {
                size_t row = crow0 + m * 16 + kb * 4 + q;
                float rsum = 0.f;
                #pragma unroll
                for (int n = 0; n < NF; n++) {
                    float e = __expf(acc[m][n][q] * 0.015625f);
                    u16 pv = f2bf(e);
                    rsum += bf2f(pv);
                    Cg[row * (size_t)LDC + col0 + n * 16 + r16] = pv;
                }
                #pragma unroll
                for (int off = 1; off < 16; off <<= 1)
                    rsum += __shfl_xor(rsum, off);
                if (r16 == 0) atomicAdd(&rs[row], rsum);
            }
        }
    } else {
        #pragma unroll
        for (int m = 0; m < MF; m++) {
            float il[4];
            #pragma unroll
            for (int q = 0; q < 4; q++)
                il[q] = 1.0f / rs[crow0 + m * 16 + kb * 4 + q];
            #pragma unroll
            for (int n = 0; n < NF; n++) {
                #pragma unroll
                for (int q = 0; q < 4; q++) {
                    int i_loc = m * 16 + kb * 4 + q;
                    int j     = col0 + n * 16 + r16;
                    float v   = acc[m][n][q];
                    int i2 = mt * TM + wr * (TM / 2) + i_loc;
                    int t = i2 >> 6, patch = i2 & 63;
                    int c = j & 63, pr = (j >> 9) & 7, pc = (j >> 6) & 7;
                    int hh = ((patch >> 3) << 3) + pr, w2 = ((patch & 7) << 3) + pc;
                    size_t o = ((((size_t)(bi * 16 + t) << 6) + hh) << 6) + w2;
                    Cg[(o << 6) + c] = f2bf(v * il[q]);
                }
            }
        }
    }
}

// ---------------------------------------------------------------------------
// Buffers:
//   A = d_out[0,32MB): qtok -> vt' (conv_v out) -> overwritten by f32 out
//   B = ws[0,32MB)   : ktok -> xb (NHWC bf16)  -> axb (NHWC bf16)
//   C = ws[32,40MB)  : probs
//   rowsum = ws[40MB,+16KB) (memset 0); wt = ws[40MB+64KB,+144KB)
// Order: wprep, dwconv -> memset -> scores(+rowsum) -> nhwc -> conv_v -> ax
//        -> conv_c
// ---------------------------------------------------------------------------
extern "C" void kernel_launch(void* const* d_in, const int* in_sizes, int n_in,
                              void* d_out, int out_size, void* d_ws, size_t ws_size,
                              hipStream_t stream)
{
    const float* x  = (const float*)d_in[0];
    const float* qw = (const float*)d_in[1];
    const float* qb = (const float*)d_in[2];
    const float* kw = (const float*)d_in[3];
    const float* kb = (const float*)d_in[4];
    const float* vw = (const float*)d_in[5];
    const float* vb = (const float*)d_in[6];
    const float* cw = (const float*)d_in[7];
    const float* cb = (const float*)d_in[8];
    float* out = (float*)d_out;

    char* ws = (char*)d_ws;
    u16*   qtok  = (u16*)d_out;                              // region A
    u16*   ktok  = (u16*)ws;                                 // region B
    u16*   probs = (u16*)(ws + (size_t)32 * 1024 * 1024);    // region C
    float* rowsum= (float*)(ws + (size_t)40 * 1024 * 1024);
    u16*   wtv   = (u16*)(ws + (size_t)40 * 1024 * 1024 + 65536);
    u16*   wtc   = wtv + 36864;
    u16*   xbuf  = ktok;                                     // B (after scores)
    u16*   vt    = qtok;                                     // A (after scores)
    u16*   axb   = ktok;                                     // B (after conv_v)

    weight_prep2<<<288, 256, 0, stream>>>(vw, cw, wtv);

    dwconv_qk<<<4096, 256, 0, stream>>>(x, qw, qb, kw, kb, qtok, ktok);

    hipMemsetAsync(rowsum, 0, 4096 * sizeof(float), stream);

    // scores: 64x128 tiles, grid 512, fused rowsum
    mfma_abt<64, 128, 4096, 4096, 1024, 4096, 16, 8, 0, 2><<<512, 256, 0, stream>>>(
        qtok, ktok, rowsum, probs);

    nchw_to_nhwc<<<4096, 256, 0, stream>>>(x, xbuf);

    conv_mfma<false><<<512, 256, 0, stream>>>(xbuf, wtv, vb, nullptr, vt, nullptr);

    // ax: 128x128 tiles, grid 1024
    mfma_abt<128, 128, 1024, 1024, 4096, 1024, 8, 32, 2, 4><<<1024, 256, 0, stream>>>(
        probs, vt, rowsum, axb);

    conv_mfma<true><<<512, 256, 0, stream>>>(axb, wtc, cb, x, nullptr, out);
}